// Round 4
// baseline (712.262 us; speedup 1.0000x reference)
//
#include <hip/hip_runtime.h>

#define NT 320          // threads/block (5 waves)
#define TZ 4
#define TH 4
#define PZ 6            // TZ+2
#define PH 6            // TH+2
#define STR 84          // LDS row stride in floats (21 float4 slots; odd slot stride de-phases rows)
#define PROWS (PZ*PH)   // 36 rows per channel tile
#define NSLOT (PROWS*20)// 720 float4 staging slots per channel

__device__ __forceinline__ void store_f4u(float* p, float4 v) {
    __builtin_memcpy(p, &v, 16);   // unaligned-safe 16B store
}

// Barrier with ONLY the semantically-required LDS drain. __syncthreads()
// makes hipcc emit s_waitcnt vmcnt(0) before s_barrier, which drains the
// in-flight y/x prefetch loads every iteration and serializes the pipeline
// (round1 vs round3 exact-null evidence). Correctness here needs lgkmcnt(0)
// only: both cross-wave hazards (ds_write visibility, read-before-overwrite)
// are LDS ops; vmcnt waits on prefetch regs are data-dependency-generated.
__device__ __forceinline__ void block_sync_lds() {
    asm volatile("s_waitcnt lgkmcnt(0)" ::: "memory");
    __builtin_amdgcn_s_barrier();
}

__global__ __launch_bounds__(NT)
void wincorr_kernel(const float* __restrict__ x, const float* __restrict__ y,
                    float* __restrict__ out)
{
    __shared__ __align__(16) float buf[2][PROWS * STR];

    const long long plane = 512000;  // 80*80*80
    const int tid = threadIdx.x;
    const int twi = tid % 20;        // float4 column within row (w = 4*twi)
    const int th  = (tid / 20) % TH;
    const int tz  = tid / 80;

    const int zt = blockIdx.x, ht = blockIdx.y, b = blockIdx.z;
    const int z0 = zt * TZ, h0 = ht * TH;
    const int gz = z0 + tz, gh = h0 + th, wb = 4 * twi;

    const float* xb = x + (long long)b * 64 * plane;
    const float* yb = y + (long long)b * 64 * plane;
    const long long xoff = (long long)gz * 6400 + gh * 80 + wb;
    // clamped offsets for the two edge scalars of x (loaded value unused at true w-edges)
    const long long xoffm = xoff - (wb > 0 ? 1 : 0);   // x[wb-1]
    const long long xoffp = xoff + (wb < 76 ? 4 : 3);  // x[wb+4]

    // ---- staging precompute: 3 float4 slots per thread (720 slots total) ----
    int  goff[3], loff[3];
    bool val[3];
    const bool inr2 = (tid + 2 * NT) < NSLOT;   // k=0,1 always in range
#pragma unroll
    for (int k = 0; k < 3; ++k) {
        int s   = tid + k * NT;
        int row = s / 20, col = s % 20;
        int pz = row / PH, py = row % PH;
        int yz = z0 - 1 + pz, yh = h0 - 1 + py;
        bool ok = (s < NSLOT) && ((unsigned)yz < 80u) && ((unsigned)yh < 80u);
        val[k]  = ok;
        goff[k] = yz * 6400 + yh * 80 + 4 * col;
        loff[k] = row * STR + 4 * col;
    }

    float4 acc[27];
#pragma unroll
    for (int o = 0; o < 27; ++o) acc[o] = make_float4(0.f, 0.f, 0.f, 0.f);

    const float4 zero4 = make_float4(0.f, 0.f, 0.f, 0.f);

    // ---- prologue ----
    // stage channel 0 directly into buf[0]
    {
        const float* yc = yb;
        float4 t0 = val[0] ? *(const float4*)(yc + goff[0]) : zero4;
        float4 t1 = val[1] ? *(const float4*)(yc + goff[1]) : zero4;
        float4 t2 = val[2] ? *(const float4*)(yc + goff[2]) : zero4;
        *(float4*)(&buf[0][loff[0]]) = t0;
        *(float4*)(&buf[0][loff[1]]) = t1;
        if (inr2) *(float4*)(&buf[0][loff[2]]) = t2;
    }
    // yA = y(1) in flight; xA = x(0) in flight
    float4 yA0, yA1, yA2, yB0 = zero4, yB1 = zero4, yB2 = zero4;
    {
        const float* yc = yb + plane;
        yA0 = val[0] ? *(const float4*)(yc + goff[0]) : zero4;
        yA1 = val[1] ? *(const float4*)(yc + goff[1]) : zero4;
        yA2 = val[2] ? *(const float4*)(yc + goff[2]) : zero4;
    }
    float4 xvA = *(const float4*)(xb + xoff);
    float  xmA = xb[xoffm];
    float  xpA = xb[xoffp];
    float4 xvB = zero4; float xmB = 0.f, xpB = 0.f;

    block_sync_lds();

#pragma unroll 2
    for (int c = 0; c < 64; ++c) {
        // write y(c+1) into buf[(c+1)&1] right after the barrier:
        // its previous readers (iter c-1) synced at the last barrier, and the
        // vmcnt on yA* was issued ~1.5 iterations ago -> no stall.
        if (c < 63) {
            float* W = (float*)buf[(c + 1) & 1];
            *(float4*)(W + loff[0]) = yA0;
            *(float4*)(W + loff[1]) = yA1;
            if (inr2) *(float4*)(W + loff[2]) = yA2;
        }
        // issue y(c+2) loads (consumed by the ds_write at top of iter c+1)
        if (c < 62) {
            const float* yc = yb + (long long)(c + 2) * plane;
            yB0 = val[0] ? *(const float4*)(yc + goff[0]) : zero4;
            yB1 = val[1] ? *(const float4*)(yc + goff[1]) : zero4;
            yB2 = val[2] ? *(const float4*)(yc + goff[2]) : zero4;
        }
        // issue x(c+1) loads (consumed by iter c+1's compute)
        if (c < 63) {
            const float* xcp = xb + (long long)(c + 1) * plane;
            xvB = *(const float4*)(xcp + xoff);
            xmB = xcp[xoffm];
            xpB = xcp[xoffp];
        }

        const float* B = buf[c & 1];
        const float4 xv = xvA; const float xml = xmA, xpr = xpA;
#pragma unroll
        for (int dz = 0; dz < 3; ++dz) {
#pragma unroll
            for (int dy = 0; dy < 3; ++dy) {
                // single aligned b128 per tap-row: y[row][wb..wb+3]
                const float4 r = *(const float4*)(B + ((tz + dz) * PH + (th + dy)) * STR + wb);
                const int o = (dz * 3 + dy) * 3;
                // t=0 (dx=-1): outputs [wb+1..wb+4] = x[wb+1..wb+4] * y[wb..wb+3]
                acc[o].x   += xv.y * r.x; acc[o].y   += xv.z * r.y;
                acc[o].z   += xv.w * r.z; acc[o].w   += xpr  * r.w;
                // t=1 (dx= 0): outputs [wb..wb+3]
                acc[o+1].x += xv.x * r.x; acc[o+1].y += xv.y * r.y;
                acc[o+1].z += xv.z * r.z; acc[o+1].w += xv.w * r.w;
                // t=2 (dx=+1): outputs [wb-1..wb+2] = x[wb-1..wb+2] * y[wb..wb+3]
                acc[o+2].x += xml  * r.x; acc[o+2].y += xv.x * r.y;
                acc[o+2].z += xv.y * r.z; acc[o+2].w += xv.z * r.w;
            }
        }

        block_sync_lds();
        // rotate prefetch registers
        xvA = xvB; xmA = xmB; xpA = xpB;
        yA0 = yB0; yA1 = yB1; yA2 = yB2;
    }

    // epilogue: scale by 64^-0.5 = 0.125; shifted windows per dx tap
    float* ob = out + (long long)b * 27 * plane + xoff;
#pragma unroll
    for (int dz = 0; dz < 3; ++dz) {
#pragma unroll
        for (int dy = 0; dy < 3; ++dy) {
            const int o = (dz * 3 + dy) * 3;
            float4 a0 = acc[o], a1 = acc[o+1], a2 = acc[o+2];
            a0.x *= 0.125f; a0.y *= 0.125f; a0.z *= 0.125f; a0.w *= 0.125f;
            a1.x *= 0.125f; a1.y *= 0.125f; a1.z *= 0.125f; a1.w *= 0.125f;
            a2.x *= 0.125f; a2.y *= 0.125f; a2.z *= 0.125f; a2.w *= 0.125f;
            float* p0 = ob + (long long)(o    ) * plane;
            float* p1 = ob + (long long)(o + 1) * plane;
            float* p2 = ob + (long long)(o + 2) * plane;
            // t=0 (dx=-1): window [wb+1..wb+4]
            if (twi < 19) store_f4u(p0 + 1, a0);
            else { p0[1] = a0.x; p0[2] = a0.y; p0[3] = a0.z; }  // w=77,78,79; drop w=80
            if (twi == 0) p0[0] = 0.f;                          // out[w=0] = x[0]*y[-1] = 0
            // t=1 (dx=0): aligned at wb
            *(float4*)p1 = a1;
            // t=2 (dx=+1): window [wb-1..wb+2]
            if (twi > 0) store_f4u(p2 - 1, a2);
            else { p2[0] = a2.y; p2[1] = a2.z; p2[2] = a2.w; }  // w=0,1,2; drop w=-1
            if (twi == 19) p2[3] = 0.f;                         // out[w=79] = x[79]*y[80] = 0
        }
    }
}

extern "C" void kernel_launch(void* const* d_in, const int* in_sizes, int n_in,
                              void* d_out, int out_size, void* d_ws, size_t ws_size,
                              hipStream_t stream) {
    const float* x = (const float*)d_in[0];
    const float* y = (const float*)d_in[1];
    float* out = (float*)d_out;

    dim3 grid(80 / TZ, 80 / TH, 2);   // (20, 20, 2) = 800 blocks
    dim3 block(NT);
    wincorr_kernel<<<grid, block, 0, stream>>>(x, y, out);
}

// Round 5
// 623.542 us; speedup vs baseline: 1.1423x; 1.1423x over previous
//
#include <hip/hip_runtime.h>

#define NT 320          // threads/block (5 waves)
#define TZ 4
#define TH 4
#define PZ 6            // TZ+2
#define PH 6            // TH+2
#define STR 84          // LDS row stride in floats (21 float4 slots; odd slot stride de-phases rows)
#define PROWS (PZ*PH)   // 36 rows per channel tile
#define NSLOT (PROWS*20)// 720 float4 staging slots per channel

__device__ __forceinline__ void store_f4u(float* p, float4 v) {
    __builtin_memcpy(p, &v, 16);   // unaligned-safe 16B store
}

// Barrier with ONLY the semantically-required LDS drain (keeps VMEM in flight).
__device__ __forceinline__ void block_sync_lds() {
    asm volatile("s_waitcnt lgkmcnt(0)" ::: "memory");
    __builtin_amdgcn_s_barrier();
}

__global__ __launch_bounds__(NT)
void wincorr_kernel(const float* __restrict__ x, const float* __restrict__ y,
                    float* __restrict__ out)
{
    __shared__ __align__(16) float buf[2][PROWS * STR];

    const long long plane = 512000;  // 80*80*80
    const int tid = threadIdx.x;
    const int twi = tid % 20;        // float4 column within row (w = 4*twi)
    const int th  = (tid / 20) % TH;
    const int tz  = tid / 80;

    const int zt = blockIdx.x, ht = blockIdx.y, b = blockIdx.z;
    const int z0 = zt * TZ, h0 = ht * TH;
    const int gz = z0 + tz, gh = h0 + th, wb = 4 * twi;

    const float* xb = x + (long long)b * 64 * plane;
    const float* yb = y + (long long)b * 64 * plane;
    const long long xoff = (long long)gz * 6400 + gh * 80 + wb;
    const long long xoffm = xoff - (wb > 0 ? 1 : 0);   // x[wb-1] (clamped; unused at edge)
    const long long xoffp = xoff + (wb < 76 ? 4 : 3);  // x[wb+4] (clamped; unused at edge)

    // ---- staging precompute: 3 float4 slots per thread (720 slots total) ----
    int  goff[3], loff[3];
    bool val[3];
    const bool inr2 = (tid + 2 * NT) < NSLOT;   // k=0,1 always in range
#pragma unroll
    for (int k = 0; k < 3; ++k) {
        int s   = tid + k * NT;
        int row = s / 20, col = s % 20;
        int pz = row / PH, py = row % PH;
        int yz = z0 - 1 + pz, yh = h0 - 1 + py;
        bool ok = (s < NSLOT) && ((unsigned)yz < 80u) && ((unsigned)yh < 80u);
        val[k]  = ok;
        goff[k] = yz * 6400 + yh * 80 + 4 * col;
        loff[k] = row * STR + 4 * col;
    }

    float4 acc[27];
#pragma unroll
    for (int o = 0; o < 27; ++o) acc[o] = make_float4(0.f, 0.f, 0.f, 0.f);

    const float4 zero4 = make_float4(0.f, 0.f, 0.f, 0.f);

    // inner compute phase: 9 tap-rows, 1 aligned b128 each, 108 FMAs
    auto compute = [&](const float* B, float4 xv, float xml, float xpr) {
#pragma unroll
        for (int dz = 0; dz < 3; ++dz) {
#pragma unroll
            for (int dy = 0; dy < 3; ++dy) {
                const float4 r = *(const float4*)(B + ((tz + dz) * PH + (th + dy)) * STR + wb);
                const int o = (dz * 3 + dy) * 3;
                // t=0 (dx=-1): outputs [wb+1..wb+4]
                acc[o].x   += xv.y * r.x; acc[o].y   += xv.z * r.y;
                acc[o].z   += xv.w * r.z; acc[o].w   += xpr  * r.w;
                // t=1 (dx= 0): outputs [wb..wb+3]
                acc[o+1].x += xv.x * r.x; acc[o+1].y += xv.y * r.y;
                acc[o+1].z += xv.z * r.z; acc[o+1].w += xv.w * r.w;
                // t=2 (dx=+1): outputs [wb-1..wb+2]
                acc[o+2].x += xml  * r.x; acc[o+2].y += xv.x * r.y;
                acc[o+2].z += xv.y * r.z; acc[o+2].w += xv.z * r.w;
            }
        }
    };

    // ---- prologue ----
    // stage channel 0 directly into buf[0]
    {
        const float* yc = yb;
        float4 t0 = val[0] ? *(const float4*)(yc + goff[0]) : zero4;
        float4 t1 = val[1] ? *(const float4*)(yc + goff[1]) : zero4;
        float4 t2 = val[2] ? *(const float4*)(yc + goff[2]) : zero4;
        *(float4*)(&buf[0][loff[0]]) = t0;
        *(float4*)(&buf[0][loff[1]]) = t1;
        if (inr2) *(float4*)(&buf[0][loff[2]]) = t2;
    }
    // yA = y(1) in flight; xA = x(0) in flight
    float4 yA0, yA1, yA2;
    {
        const float* yc = yb + plane;
        yA0 = val[0] ? *(const float4*)(yc + goff[0]) : zero4;
        yA1 = val[1] ? *(const float4*)(yc + goff[1]) : zero4;
        yA2 = val[2] ? *(const float4*)(yc + goff[2]) : zero4;
    }
    float4 xvA = *(const float4*)(xb + xoff);
    float  xmA = xb[xoffm];
    float  xpA = xb[xoffp];

    block_sync_lds();

    // ---- steady state: c = 0..61, ZERO interior branches ----
    // All global loads unconditional (c+2 <= 63, c+1 <= 62): the compiler can
    // statically count outstanding VMEM ops and emit counted vmcnt waits, so
    // the ds_write of y(c+1) (loaded one body earlier) never eats a full
    // load latency. Previous rounds' `if (c<63)` branch-joins forced
    // conservative vmcnt(0)-style waits every iteration -> 355us plateau.
#pragma unroll 2
    for (int c = 0; c < 62; ++c) {
        // 1. write y(c+1) into buf[(c+1)&1] (readers of this buffer synced
        //    at the previous barrier; yA loads issued one body ago)
        float* W = (float*)buf[(c + 1) & 1];
        *(float4*)(W + loff[0]) = yA0;
        *(float4*)(W + loff[1]) = yA1;
        if (inr2) *(float4*)(W + loff[2]) = yA2;

        // 2. issue y(c+2) loads (consumed by step 1 of body c+1)
        const float* yc = yb + (long long)(c + 2) * plane;
        float4 yB0 = val[0] ? *(const float4*)(yc + goff[0]) : zero4;
        float4 yB1 = val[1] ? *(const float4*)(yc + goff[1]) : zero4;
        float4 yB2 = val[2] ? *(const float4*)(yc + goff[2]) : zero4;

        // 3. issue x(c+1) loads (consumed by step 4 of body c+1)
        const float* xcp = xb + (long long)(c + 1) * plane;
        float4 xvB = *(const float4*)(xcp + xoff);
        float  xmB = xcp[xoffm];
        float  xpB = xcp[xoffp];

        // 4. compute channel c from buf[c&1]
        compute(buf[c & 1], xvA, xmA, xpA);

        block_sync_lds();
        // rotate prefetch registers
        xvA = xvB; xmA = xmB; xpA = xpB;
        yA0 = yB0; yA1 = yB1; yA2 = yB2;
    }

    // ---- peeled tail: c = 62 (last ds_write + last x prefetch, no y loads) ----
    {
        float* W = (float*)buf[1];
        *(float4*)(W + loff[0]) = yA0;   // y(63)
        *(float4*)(W + loff[1]) = yA1;
        if (inr2) *(float4*)(W + loff[2]) = yA2;

        const float* xcp = xb + 63LL * plane;
        float4 xvB = *(const float4*)(xcp + xoff);
        float  xmB = xcp[xoffm];
        float  xpB = xcp[xoffp];

        compute(buf[0], xvA, xmA, xpA);  // channel 62

        block_sync_lds();
        xvA = xvB; xmA = xmB; xpA = xpB;
    }
    // ---- peeled tail: c = 63 (compute only) ----
    compute(buf[1], xvA, xmA, xpA);

    // epilogue: scale by 64^-0.5 = 0.125; shifted windows per dx tap
    float* ob = out + (long long)b * 27 * plane + xoff;
#pragma unroll
    for (int dz = 0; dz < 3; ++dz) {
#pragma unroll
        for (int dy = 0; dy < 3; ++dy) {
            const int o = (dz * 3 + dy) * 3;
            float4 a0 = acc[o], a1 = acc[o+1], a2 = acc[o+2];
            a0.x *= 0.125f; a0.y *= 0.125f; a0.z *= 0.125f; a0.w *= 0.125f;
            a1.x *= 0.125f; a1.y *= 0.125f; a1.z *= 0.125f; a1.w *= 0.125f;
            a2.x *= 0.125f; a2.y *= 0.125f; a2.z *= 0.125f; a2.w *= 0.125f;
            float* p0 = ob + (long long)(o    ) * plane;
            float* p1 = ob + (long long)(o + 1) * plane;
            float* p2 = ob + (long long)(o + 2) * plane;
            // t=0 (dx=-1): window [wb+1..wb+4]
            if (twi < 19) store_f4u(p0 + 1, a0);
            else { p0[1] = a0.x; p0[2] = a0.y; p0[3] = a0.z; }  // w=77,78,79; drop w=80
            if (twi == 0) p0[0] = 0.f;                          // out[w=0] = x[0]*y[-1] = 0
            // t=1 (dx=0): aligned at wb
            *(float4*)p1 = a1;
            // t=2 (dx=+1): window [wb-1..wb+2]
            if (twi > 0) store_f4u(p2 - 1, a2);
            else { p2[0] = a2.y; p2[1] = a2.z; p2[2] = a2.w; }  // w=0,1,2; drop w=-1
            if (twi == 19) p2[3] = 0.f;                         // out[w=79] = x[79]*y[80] = 0
        }
    }
}

extern "C" void kernel_launch(void* const* d_in, const int* in_sizes, int n_in,
                              void* d_out, int out_size, void* d_ws, size_t ws_size,
                              hipStream_t stream) {
    const float* x = (const float*)d_in[0];
    const float* y = (const float*)d_in[1];
    float* out = (float*)d_out;

    dim3 grid(80 / TZ, 80 / TH, 2);   // (20, 20, 2) = 800 blocks
    dim3 block(NT);
    wincorr_kernel<<<grid, block, 0, stream>>>(x, y, out);
}